// Round 2
// baseline (880.816 us; speedup 1.0000x reference)
//
#include <hip/hip_runtime.h>
#include <hip/hip_bf16.h>
#include <hip/hip_fp16.h>

#define QN    50
#define NWAY  5
#define MM    196
#define KMM   980
#define DD    640
#define KP    992      // k padded to 31 tiles of 32
#define MT    7        // m tiles of 32 (224 rows, pad)
#define KT    31
#define NITER 5

typedef __attribute__((ext_vector_type(8)))  short short8;
typedef __attribute__((ext_vector_type(16))) float f32x16;

#define EXP2F(x) __builtin_exp2f(x)
#define LOG2F(x) __builtin_log2f(x)

__device__ __forceinline__ short bf16bits(float f) {
  __hip_bfloat16 h = __float2bfloat16(f);
  return *reinterpret_cast<short*>(&h);
}

__global__ __launch_bounds__(512, 2)
void sink_kernel(const float* __restrict__ qt, const float* __restrict__ st,
                 const float* __restrict__ var, const float* __restrict__ epsr,
                 const float* __restrict__ taur, float* __restrict__ out,
                 __half* __restrict__ cost, int q0)
{
  __shared__ __align__(16) float w_lds[DD];
  __shared__ __align__(16) float v2[KP];
  __shared__ float u2[MM];
  __shared__ float red_s;

  const int tid  = threadIdx.x;
  const int wave = tid >> 6;
  const int lane = tid & 63;
  const int l31  = lane & 31;
  const int lh   = lane >> 5;

  const int pair = blockIdx.x;
  const int qi = q0 + pair / NWAY;
  const int wi = pair % NWAY;

  const float eps = logf(1.0f + expf(epsr[0])) + 1e-4f;
  const float tau = logf(1.0f + expf(taur[0])) + 0.01f;
  const float C2  = 1.4426950408889634f / eps;   // log2(e)/eps ; logK2 = (sim-1)*C2

  // ---- per-dim weights: w = inv/(sum inv) * D ----
  float psum = 0.f;
  for (int d = tid; d < DD; d += 512) {
    float inv = 1.0f / (var[wi * DD + d] + 0.01f);
    w_lds[d] = inv;
    psum += inv;
  }
  #pragma unroll
  for (int s = 32; s; s >>= 1) psum += __shfl_xor(psum, s);
  if (tid == 0) red_s = 0.f;
  __syncthreads();
  if (lane == 0) atomicAdd(&red_s, psum);
  __syncthreads();
  const float wscale = (float)DD / fmaxf(red_s, 1e-6f);
  for (int d = tid; d < DD; d += 512) w_lds[d] *= wscale;
  __syncthreads();

  // ---- GEMM phase: cost[m][k] = fp16( (sim-1)*C2 ), sentinel for k>=980 ----
  const float* qbase = qt + (size_t)qi * MM * DD;
  const float* sbase = st + (size_t)wi * KMM * DD;
  __half* cbase = cost + (size_t)pair * (MM * KP);

  for (int strip = 0; strip < 4; ++strip) {
    const int ktile = strip * 8 + wave;
    if (ktile >= KT) continue;               // no barriers inside this loop
    const int k0 = ktile * 32;
    const int krow = k0 + l31;
    const float* srow = sbase + (size_t)min(krow, KMM - 1) * DD + lh * 8;

    f32x16 acc[MT];
    #pragma unroll
    for (int t = 0; t < MT; ++t) {
      #pragma unroll
      for (int e = 0; e < 16; ++e) acc[t][e] = 0.f;
    }

    for (int ds = 0; ds < DD / 16; ++ds) {
      const int d0 = ds * 16 + lh * 8;
      float4 w0 = *reinterpret_cast<const float4*>(w_lds + d0);
      float4 w1 = *reinterpret_cast<const float4*>(w_lds + d0 + 4);
      float4 s0 = *reinterpret_cast<const float4*>(srow + ds * 16);
      float4 s1 = *reinterpret_cast<const float4*>(srow + ds * 16 + 4);
      short8 b;
      b[0] = bf16bits(s0.x * w0.x); b[1] = bf16bits(s0.y * w0.y);
      b[2] = bf16bits(s0.z * w0.z); b[3] = bf16bits(s0.w * w0.w);
      b[4] = bf16bits(s1.x * w1.x); b[5] = bf16bits(s1.y * w1.y);
      b[6] = bf16bits(s1.z * w1.z); b[7] = bf16bits(s1.w * w1.w);
      #pragma unroll
      for (int mt = 0; mt < MT; ++mt) {
        const int mr = mt * 32 + l31;
        const float* qrow = qbase + (size_t)min(mr, MM - 1) * DD + d0;
        float4 a0 = *reinterpret_cast<const float4*>(qrow);
        float4 a1 = *reinterpret_cast<const float4*>(qrow + 4);
        short8 a;
        a[0] = bf16bits(a0.x); a[1] = bf16bits(a0.y);
        a[2] = bf16bits(a0.z); a[3] = bf16bits(a0.w);
        a[4] = bf16bits(a1.x); a[5] = bf16bits(a1.y);
        a[6] = bf16bits(a1.z); a[7] = bf16bits(a1.w);
        acc[mt] = __builtin_amdgcn_mfma_f32_32x32x16_bf16(a, b, acc[mt], 0, 0, 0);
      }
    }
    // epilogue: C/D layout col=lane&31 (k), row=(r&3)+8*(r>>2)+4*(lane>>5) (m)
    #pragma unroll
    for (int mt = 0; mt < MT; ++mt) {
      #pragma unroll
      for (int r = 0; r < 16; ++r) {
        const int mrow = mt * 32 + (r & 3) + 8 * (r >> 2) + 4 * lh;
        if (mrow < MM) {
          const int kcol = k0 + l31;
          const float val = (kcol < KMM) ? (acc[mt][r] - 1.0f) * C2 : -60000.0f;
          cbase[(size_t)mrow * KP + kcol] = __float2half(val);
        }
      }
    }
  }

  for (int i = tid; i < MM; i += 512) u2[i] = 0.f;
  if (tid == 0) red_s = 0.f;
  __syncthreads();   // drains vmcnt -> cost writes visible block-wide (same XCD L2)

  const float L2M = 7.6147098441152083f;   // log2(196)
  const float L2K = 9.9366379390935392f;   // log2(980)

  for (int it = 0; it < NITER; ++it) {
    // ---- v update: thread owns cols 2t,2t+1 ; reduce over m ----
    if (tid < KP / 2) {
      const int kc = 2 * tid;
      const __half* cp = cbase + kc;
      float Sa = 0.f, Sb = 0.f;
      #pragma unroll 4
      for (int m = 0; m < MM; ++m) {
        __half2 hv = *reinterpret_cast<const __half2*>(cp + (size_t)m * KP);
        float2 f = __half22float2(hv);
        const float u = u2[m];
        Sa += EXP2F(f.x + u);
        Sb += EXP2F(f.y + u);
      }
      v2[kc]     = (kc     < KMM) ? (-L2K - LOG2F(Sa)) : -1e30f;
      v2[kc + 1] = (kc + 1 < KMM) ? (-L2K - LOG2F(Sb)) : -1e30f;
    }
    __syncthreads();
    // ---- u update: wave per row, lanes split k ; final iter fuses gamma*cost ----
    const bool fin = (it == NITER - 1);
    for (int i = 0; i < 25; ++i) {
      const int m = i * 8 + wave;
      if (m < MM) {
        const __half* rp = cbase + (size_t)m * KP;
        float A = 0.f, B = 0.f;
        #pragma unroll
        for (int j = 0; j < 4; ++j) {
          const int k = 4 * lane + 256 * j;
          if (k < KP) {
            uint2 raw = *reinterpret_cast<const uint2*>(rp + k);
            __half2 h01 = *reinterpret_cast<const __half2*>(&raw.x);
            __half2 h23 = *reinterpret_cast<const __half2*>(&raw.y);
            float4 vv = *reinterpret_cast<const float4*>(v2 + k);
            float2 f01 = __half22float2(h01);
            float2 f23 = __half22float2(h23);
            float e0 = EXP2F(f01.x + vv.x);
            float e1 = EXP2F(f01.y + vv.y);
            float e2 = EXP2F(f23.x + vv.z);
            float e3 = EXP2F(f23.y + vv.w);
            A += (e0 + e1) + (e2 + e3);
            if (fin) B += e0 * f01.x + e1 * f01.y + e2 * f23.x + e3 * f23.y;
          }
        }
        #pragma unroll
        for (int s = 32; s; s >>= 1) {
          A += __shfl_xor(A, s);
          if (fin) B += __shfl_xor(B, s);
        }
        if (lane == 0) {
          u2[m] = -L2M - LOG2F(A);
          // ot contribution: sum_k gamma*cost = -B/(196*C2*A) (2^u folded in)
          if (fin) atomicAdd(&red_s, -B / ((float)MM * C2 * A));
        }
      }
    }
    __syncthreads();
  }

  if (tid == 0) out[(size_t)qi * NWAY + wi] = -red_s / tau;
}

extern "C" void kernel_launch(void* const* d_in, const int* in_sizes, int n_in,
                              void* d_out, int out_size, void* d_ws, size_t ws_size,
                              hipStream_t stream) {
  const float* qt  = (const float*)d_in[0];
  const float* st  = (const float*)d_in[1];
  const float* var = (const float*)d_in[2];
  const float* er  = (const float*)d_in[3];
  const float* tr  = (const float*)d_in[4];
  float* out = (float*)d_out;
  __half* ws = (__half*)d_ws;

  // cost scratch: per query = 5 pairs * 196*992 fp16  (~1.9 MB). Chunk queries
  // if ws is small; single launch of 250 blocks when ws >= ~97 MB.
  const size_t per_q = (size_t)NWAY * MM * KP * sizeof(__half);
  int qpc = (int)(ws_size / per_q);
  if (qpc < 1) qpc = 1;
  if (qpc > QN) qpc = QN;
  for (int q0 = 0; q0 < QN; q0 += qpc) {
    const int nq = (QN - q0 < qpc) ? (QN - q0) : qpc;
    sink_kernel<<<nq * NWAY, 512, 0, stream>>>(qt, st, var, er, tr, out, ws, q0);
  }
}